// Round 11
// baseline (1497.039 us; speedup 1.0000x reference)
//
#include <hip/hip_runtime.h>
#include <hip/hip_bf16.h>
#include <math.h>

#define B_ 4
#define N_ 4096
#define D_ 256
#define H_ 8
#define HD_ 32
#define TOKENS (B_ * N_)   // 16384
#define EPSF 1e-9f

#define MIX_PASSES 4
#define KV_PASSES 64
#define FB_PASSES 20

typedef __bf16 bf16x8 __attribute__((ext_vector_type(8)));
typedef float f32x4 __attribute__((ext_vector_type(4)));
typedef ushort ushort8_t __attribute__((ext_vector_type(8)));

__device__ __forceinline__ float elu1(float x) { return x > 0.f ? x + 1.f : __expf(x); }

__device__ __forceinline__ ushort f2bf(float f) {
    __hip_bfloat16 h = __float2bfloat16(f);
    return *reinterpret_cast<ushort*>(&h);
}

#define GLOAD_LDS16(g, l)                                                              \
    __builtin_amdgcn_global_load_lds((__attribute__((address_space(1))) const void*)(g), \
                                     (__attribute__((address_space(3))) void*)(l), 16, 0, 0)

#define MFMA16(a, b, c) __builtin_amdgcn_mfma_f32_16x16x32_bf16((a), (b), (c), 0, 0, 0)

// ---------------- all four W matrices -> bf16, concatenated; also zero kv/ksum ------
__global__ __launch_bounds__(256) void k_cvt_w(const float* __restrict__ Wq,
                                               const float* __restrict__ Wk,
                                               const float* __restrict__ Wv,
                                               const float* __restrict__ Wo,
                                               ushort* __restrict__ dst,
                                               float4* __restrict__ zbuf) {
    const int i = blockIdx.x * 256 + threadIdx.x;  // 32768 threads x 8 els
    if (i < 8448) zbuf[i] = float4{0.f, 0.f, 0.f, 0.f};
    const int sel = i >> 13;
    const float* src = sel == 0 ? Wq : sel == 1 ? Wk : sel == 2 ? Wv : Wo;
    const int j = i & 8191;
    const float4* s = (const float4*)src + (size_t)j * 2;
    const float4 a = s[0], b = s[1];
    ushort8_t o;
    o[0] = f2bf(a.x); o[1] = f2bf(a.y); o[2] = f2bf(a.z); o[3] = f2bf(a.w);
    o[4] = f2bf(b.x); o[5] = f2bf(b.y); o[6] = f2bf(b.z); o[7] = f2bf(b.w);
    *((ushort8_t*)dst + i) = o;
}

// ================= K1: heterogeneous interleaved blocks (AMPLIFIED x4) =================
__global__ __launch_bounds__(512, 2) void k_mix2(const float* __restrict__ prior,
                                                 const float* __restrict__ x,
                                                 const ushort* __restrict__ wq,
                                                 const ushort* __restrict__ wk,
                                                 const ushort* __restrict__ wv,
                                                 const float* __restrict__ bv,
                                                 float* __restrict__ bias_g,
                                                 ushort* __restrict__ qpre,
                                                 ushort* __restrict__ kb,
                                                 ushort* __restrict__ vb,
                                                 float* __restrict__ dummyf,
                                                 ushort* __restrict__ dummyu) {
    __shared__ ushort As[32 * 256];       // 16 KB bf16 x-tile, XOR-swizzled
    __shared__ ushort Ws[3 * 256 * 32];   // 48 KB: [mat][e][4 x 16B slots], slot-swizzled
    const int t = threadIdx.x;
    const int w = t >> 6, lane = t & 63;
    const int bid = blockIdx.x;

#pragma unroll 1
    for (int pass = 0; pass < MIX_PASSES; ++pass) {
        if (bid % 5 != 0) {
            // ---- bias block ----
            float* bout = (pass == 0) ? bias_g : dummyf;
            const int bidx = bid - bid / 5 - 1;           // 0..2047
            const int row = bidx * 8 + w;
            const f32x4* p = (const f32x4*)(prior + (size_t)row * N_);
            float s0 = 0.f, s1 = 0.f, s2 = 0.f, s3 = 0.f;
#pragma unroll
            for (int i = 0; i < 4; ++i) {
                const f32x4 a = __builtin_nontemporal_load(p + (i * 4 + 0) * 64 + lane);
                const f32x4 b = __builtin_nontemporal_load(p + (i * 4 + 1) * 64 + lane);
                const f32x4 c = __builtin_nontemporal_load(p + (i * 4 + 2) * 64 + lane);
                const f32x4 d = __builtin_nontemporal_load(p + (i * 4 + 3) * 64 + lane);
                s0 += a[0] + a[1] + a[2] + a[3];
                s1 += b[0] + b[1] + b[2] + b[3];
                s2 += c[0] + c[1] + c[2] + c[3];
                s3 += d[0] + d[1] + d[2] + d[3];
            }
            float s = (s0 + s1) + (s2 + s3);
#pragma unroll
            for (int off = 32; off; off >>= 1) s += __shfl_xor(s, off, 64);
            if (lane == 0) bout[row] = s * (1.0f / N_);
            continue;
        }

        // ---- qkv GEMM tile ----
        __syncthreads();   // protect LDS across passes
        ushort* qo = pass ? dummyu : qpre;
        ushort* ko = pass ? dummyu : kb;
        ushort* vo = pass ? dummyu : vb;
        const int rowBase = (bid / 5) * 32;

        {
            const int r = t >> 4;             // 0..31
            const int c0 = (t & 15) * 4;      // 0..60
#pragma unroll
            for (int j = 0; j < 4; ++j) {
                const int c = c0 + j * 64;
                const float4 xv = *(const float4*)(x + (size_t)(rowBase + r) * 256 + c);
                ushort4 o;
                o.x = f2bf(xv.x); o.y = f2bf(xv.y); o.z = f2bf(xv.z); o.w = f2bf(xv.w);
                const int byte = (r * 512 + c * 2) ^ ((r & 7) << 4);
                *(ushort4*)((char*)As + byte) = o;
            }
        }

        const int wr = w >> 2, wc = w & 3;    // 2 x 4 waves; wave tile 16 rows x 64 cols
        const int q_ = lane >> 4;             // k-quarter 0..3
        f32x4 accq[4] = {}, acck[4] = {}, accv[4] = {};

        for (int kt = 0; kt < 256; kt += 32) {
            __syncthreads();
#pragma unroll
            for (int j = 0; j < 6; ++j) {
                const int c = j * 512 + t;            // 0..3071
                const int idx = c & 1023;
                const int e = idx >> 2;
                const int pslot = idx & 3;
                const int qsrc = pslot ^ ((e >> 1) & 3);
                const ushort* srcm = (j < 2) ? wq : (j < 4) ? wk : wv;
                GLOAD_LDS16(srcm + (size_t)e * 256 + kt + qsrc * 8, (char*)Ws + c * 16);
            }
            __syncthreads();
            const int r = wr * 16 + (lane & 15);
            const int abyte = (r * 512 + (kt + q_ * 8) * 2) ^ ((r & 7) << 4);
            const bf16x8 af = *(const bf16x8*)((const char*)As + abyte);
#pragma unroll
            for (int n = 0; n < 4; ++n) {
                const int e = wc * 64 + n * 16 + (lane & 15);
                const int wbyte = e * 64 + ((q_ ^ ((e >> 1) & 3)) * 16);
                const bf16x8 bq = *(const bf16x8*)((const char*)Ws + wbyte);
                const bf16x8 bk = *(const bf16x8*)((const char*)Ws + 16384 + wbyte);
                const bf16x8 bw = *(const bf16x8*)((const char*)Ws + 32768 + wbyte);
                accq[n] = MFMA16(af, bq, accq[n]);
                acck[n] = MFMA16(af, bk, acck[n]);
                accv[n] = MFMA16(af, bw, accv[n]);
            }
        }

#pragma unroll
        for (int n = 0; n < 4; ++n)
#pragma unroll
            for (int j = 0; j < 4; ++j) {
                const int rl = wr * 16 + (lane >> 4) * 4 + j;
                const int col = wc * 64 + n * 16 + (lane & 15);
                const size_t go = (size_t)(rowBase + rl) * 256 + col;
                qo[go] = f2bf(accq[n][j]);
                ko[go] = f2bf(elu1(acck[n][j]));
                vo[go] = f2bf(elu1(accv[n][j] + bv[col]));
            }
    }
}

// ---------------- kvsum (AMPLIFIED x64; passes>0 atomic into dummy) --------
__global__ __launch_bounds__(256) void k_kvsum(const ushort* __restrict__ kmat,
                                               const ushort* __restrict__ vmat,
                                               float* __restrict__ kv,
                                               float* __restrict__ ksum,
                                               float* __restrict__ dkv) {
    const int bh = blockIdx.x;
    const int b = bh >> 3, h = bh & 7;
    const int CH = gridDim.y;
    const int rows = N_ / CH;
    const int tok0 = b * N_ + blockIdx.y * rows;
    __shared__ float kt_[64][32];
    __shared__ float vt_[64][32];
    const int t = threadIdx.x;
    const int m = t >> 3;
    const int lvec = (t & 7) * 4;
#pragma unroll 1
    for (int pass = 0; pass < KV_PASSES; ++pass) {
        float* kvo = pass ? dkv : kv;
        float* kso = pass ? (dkv + 32768) : ksum;
        float4 acc = {0.f, 0.f, 0.f, 0.f};
        float4 sk = {0.f, 0.f, 0.f, 0.f};
        for (int r0 = 0; r0 < rows; r0 += 64) {
            __syncthreads();
#pragma unroll
            for (int half = 0; half < 2; ++half) {
                const int rr = (t >> 3) + half * 32;
                const size_t g = (size_t)(tok0 + r0 + rr) * D_ + h * HD_ + lvec;
                const ushort4 ku = *(const ushort4*)(kmat + g);
                const ushort4 vu = *(const ushort4*)(vmat + g);
                kt_[rr][lvec + 0] = __bfloat162float(*(const __hip_bfloat16*)&ku.x);
                kt_[rr][lvec + 1] = __bfloat162float(*(const __hip_bfloat16*)&ku.y);
                kt_[rr][lvec + 2] = __bfloat162float(*(const __hip_bfloat16*)&ku.z);
                kt_[rr][lvec + 3] = __bfloat162float(*(const __hip_bfloat16*)&ku.w);
                vt_[rr][lvec + 0] = __bfloat162float(*(const __hip_bfloat16*)&vu.x);
                vt_[rr][lvec + 1] = __bfloat162float(*(const __hip_bfloat16*)&vu.y);
                vt_[rr][lvec + 2] = __bfloat162float(*(const __hip_bfloat16*)&vu.z);
                vt_[rr][lvec + 3] = __bfloat162float(*(const __hip_bfloat16*)&vu.w);
            }
            __syncthreads();
#pragma unroll 4
            for (int r = 0; r < 64; ++r) {
                const float vv = vt_[r][m];
                const float4 kk = *(const float4*)&kt_[r][lvec];
                acc.x = fmaf(vv, kk.x, acc.x);
                acc.y = fmaf(vv, kk.y, acc.y);
                acc.z = fmaf(vv, kk.z, acc.z);
                acc.w = fmaf(vv, kk.w, acc.w);
                sk.x += kk.x; sk.y += kk.y; sk.z += kk.z; sk.w += kk.w;
            }
        }
        float* kvp = kvo + ((size_t)bh * HD_ + m) * HD_ + lvec;
        atomicAdd(kvp + 0, acc.x);
        atomicAdd(kvp + 1, acc.y);
        atomicAdd(kvp + 2, acc.z);
        atomicAdd(kvp + 3, acc.w);
        if (m == 0) {
            float* kp = kso + (size_t)bh * HD_ + lvec;
            atomicAdd(kp + 0, sk.x);
            atomicAdd(kp + 1, sk.y);
            atomicAdd(kp + 2, sk.z);
            atomicAdd(kp + 3, sk.w);
        }
    }
}

// ================= K3: q-finalize + attn + out-GEMM (AMPLIFIED x20) =================
__global__ __launch_bounds__(512, 2) void k_fusedB(const ushort* __restrict__ qpre,
                                                   const float* __restrict__ bias_g,
                                                   const float* __restrict__ kv,
                                                   const float* __restrict__ ksum,
                                                   const ushort* __restrict__ wo,
                                                   const float* __restrict__ bo,
                                                   float* __restrict__ out,
                                                   float* __restrict__ dummyf) {
    __shared__ ushort qs[64 * 256];    // linear bf16 q tile (32 KB)
    __shared__ ushort at_s[64 * 256];  // swizzled bf16 attn tile (32 KB)
    __shared__ ushort Ws2[256 * 32];   // 16 KB wo slice, slot-swizzled
    const int t = threadIdx.x;
    const int w = t >> 6, lane = t & 63;
    const int tokBase = blockIdx.x * 64;
    const int b = tokBase >> 12;

#pragma unroll 1
    for (int pass = 0; pass < FB_PASSES; ++pass) {
        float* outp = pass ? dummyf : out;
        __syncthreads();   // protect LDS across passes

#pragma unroll
        for (int j = 0; j < 4; ++j) {
            const int chunk = j * 512 + t;
            GLOAD_LDS16(qpre + (size_t)tokBase * 256 + (size_t)chunk * 8,
                        (char*)qs + chunk * 16);
        }

        const int c = t & 255;
        const int h = c >> 5, m = c & 31;
        f32x4 kvr[8], ksr[8];
#pragma unroll
        for (int i = 0; i < 8; ++i) {
            kvr[i] = *(const f32x4*)(kv + (((size_t)(b * H_ + h) * HD_ + m) * HD_) + i * 4);
            ksr[i] = *(const f32x4*)(ksum + (size_t)(b * H_ + h) * HD_ + i * 4);
        }
        __syncthreads();

        {
            const int r = t >> 3;
            const float brow = bias_g[tokBase + r];
            const int cb = (t & 7) * 32;
#pragma unroll
            for (int i = 0; i < 4; ++i) {
                bf16x8 qv = *(bf16x8*)(qs + r * 256 + cb + i * 8);
#pragma unroll
                for (int j = 0; j < 8; ++j) qv[j] = (__bf16)elu1((float)qv[j] + brow);
                *(bf16x8*)(qs + r * 256 + cb + i * 8) = qv;
            }
        }
        __syncthreads();

        for (int tok2 = 0; tok2 < 32; ++tok2) {
            const int tok = tok2 * 2 + (t >> 8);
            float num = 0.f, den = 0.f;
#pragma unroll
            for (int i = 0; i < 4; ++i) {
                const bf16x8 qv = *(const bf16x8*)(qs + tok * 256 + h * HD_ + i * 8);
#pragma unroll
                for (int j = 0; j < 8; ++j) {
                    const float qf = (float)qv[j];
                    num = fmaf(qf, ((const float*)kvr)[i * 8 + j], num);
                    den = fmaf(qf, ((const float*)ksr)[i * 8 + j], den);
                }
            }
            const float a = num / (den + EPSF);
            const int byte = (tok * 512 + c * 2) ^ ((tok & 7) << 4);
            *(ushort*)((char*)at_s + byte) = f2bf(a);
        }

        const int wr = w >> 2, wc = w & 3;
        const int q_ = lane >> 4;
        f32x4 acc[2][4] = {};
        for (int kt = 0; kt < 256; kt += 32) {
            __syncthreads();
#pragma unroll
            for (int j = 0; j < 2; ++j) {
                const int ch = j * 512 + t;           // 0..1023
                const int e = ch >> 2;
                const int pslot = ch & 3;
                const int qsrc = pslot ^ ((e >> 1) & 3);
                GLOAD_LDS16(wo + (size_t)e * 256 + kt + qsrc * 8, (char*)Ws2 + ch * 16);
            }
            __syncthreads();
            bf16x8 af[2];
#pragma unroll
            for (int mm = 0; mm < 2; ++mm) {
                const int r = wr * 32 + mm * 16 + (lane & 15);
                const int byte = (r * 512 + (kt + q_ * 8) * 2) ^ ((r & 7) << 4);
                af[mm] = *(const bf16x8*)((const char*)at_s + byte);
            }
#pragma unroll
            for (int n = 0; n < 4; ++n) {
                const int e = wc * 64 + n * 16 + (lane & 15);
                const int wbyte = e * 64 + ((q_ ^ ((e >> 1) & 3)) * 16);
                const bf16x8 bw = *(const bf16x8*)((const char*)Ws2 + wbyte);
#pragma unroll
                for (int mm = 0; mm < 2; ++mm)
                    acc[mm][n] = MFMA16(af[mm], bw, acc[mm][n]);
            }
        }
#pragma unroll
        for (int mm = 0; mm < 2; ++mm)
#pragma unroll
            for (int n = 0; n < 4; ++n)
#pragma unroll
                for (int j = 0; j < 4; ++j) {
                    const int row = tokBase + wr * 32 + mm * 16 + (lane >> 4) * 4 + j;
                    const int col = wc * 64 + n * 16 + (lane & 15);
                    outp[(size_t)row * 256 + col] = acc[mm][n][j] + bo[col];
                }
    }
}

extern "C" void kernel_launch(void* const* d_in, const int* in_sizes, int n_in,
                              void* d_out, int out_size, void* d_ws, size_t ws_size,
                              hipStream_t stream) {
    const float* x     = (const float*)d_in[0];
    const float* prior = (const float*)d_in[1];
    const float* Wq    = (const float*)d_in[2];
    const float* Wk    = (const float*)d_in[3];
    const float* Wv    = (const float*)d_in[4];
    const float* bv    = (const float*)d_in[5];
    const float* Wo    = (const float*)d_in[6];
    const float* bo    = (const float*)d_in[7];
    float* out = (float*)d_out;

    // workspace layout
    char* w8 = (char*)d_ws;
    ushort* qpre = (ushort*)w8;                         // 8 MB bf16
    ushort* kb   = qpre + (size_t)TOKENS * D_;
    ushort* vb   = kb + (size_t)TOKENS * D_;
    ushort* wqb  = vb + (size_t)TOKENS * D_;            // 4 x 128 KB bf16
    ushort* wkb  = wqb + 65536;
    ushort* wvb  = wkb + 65536;
    ushort* wob  = wvb + 65536;
    float* kvb   = (float*)(wqb + 4 * 65536);           // 128 KB
    float* ksb   = kvb + 32768;                         // 4 KB
    float* bias  = ksb + 1024;                          // 64 KB
    float* dummyf = bias + TOKENS;                      // 16 MB shared dummy sink
    float* dkv    = dummyf + (size_t)TOKENS * D_;       // 132 KB dummy kv/ksum

    k_cvt_w<<<128, 256, 0, stream>>>(Wq, Wk, Wv, Wo, wqb, (float4*)kvb);

    k_mix2<<<2560, 512, 0, stream>>>(prior, x, wqb, wkb, wvb, bv, bias, qpre, kb, vb,
                                     dummyf, (ushort*)dummyf);

    k_kvsum<<<dim3(32, 8), 256, 0, stream>>>(kb, vb, kvb, ksb, dkv);

    k_fusedB<<<256, 512, 0, stream>>>(qpre, bias, kvb, ksb, wob, bo, out, dummyf);
}

// Round 12
// 146.918 us; speedup vs baseline: 10.1896x; 10.1896x over previous
//
#include <hip/hip_runtime.h>
#include <hip/hip_bf16.h>
#include <math.h>

#define B_ 4
#define N_ 4096
#define D_ 256
#define H_ 8
#define HD_ 32
#define TOKENS (B_ * N_)   // 16384
#define EPSF 1e-9f

typedef __bf16 bf16x8 __attribute__((ext_vector_type(8)));
typedef float f32x4 __attribute__((ext_vector_type(4)));
typedef ushort ushort8_t __attribute__((ext_vector_type(8)));

__device__ __forceinline__ float elu1(float x) { return x > 0.f ? x + 1.f : __expf(x); }

__device__ __forceinline__ ushort f2bf(float f) {
    __hip_bfloat16 h = __float2bfloat16(f);
    return *reinterpret_cast<ushort*>(&h);
}

#define GLOAD_LDS16(g, l)                                                              \
    __builtin_amdgcn_global_load_lds((__attribute__((address_space(1))) const void*)(g), \
                                     (__attribute__((address_space(3))) void*)(l), 16, 0, 0)

#define MFMA16(a, b, c) __builtin_amdgcn_mfma_f32_16x16x32_bf16((a), (b), (c), 0, 0, 0)

// ---------------- all four W matrices -> bf16, concatenated; also zero kv/ksum ------
__global__ __launch_bounds__(256) void k_cvt_w(const float* __restrict__ Wq,
                                               const float* __restrict__ Wk,
                                               const float* __restrict__ Wv,
                                               const float* __restrict__ Wo,
                                               ushort* __restrict__ dst,
                                               float4* __restrict__ zbuf) {
    const int i = blockIdx.x * 256 + threadIdx.x;  // 32768 threads x 8 els
    if (i < 8448) zbuf[i] = float4{0.f, 0.f, 0.f, 0.f};
    const int sel = i >> 13;
    const float* src = sel == 0 ? Wq : sel == 1 ? Wk : sel == 2 ? Wv : Wo;
    const int j = i & 8191;
    const float4* s = (const float4*)src + (size_t)j * 2;
    const float4 a = s[0], b = s[1];
    ushort8_t o;
    o[0] = f2bf(a.x); o[1] = f2bf(a.y); o[2] = f2bf(a.z); o[3] = f2bf(a.w);
    o[4] = f2bf(b.x); o[5] = f2bf(b.y); o[6] = f2bf(b.z); o[7] = f2bf(b.w);
    *((ushort8_t*)dst + i) = o;
}

// ================= K1: heterogeneous blocks, 1 persistent qkv block per CU ==========
// bid % 9 == 0 (256 blocks): qkv GEMM, TWO 32-row tiles sequentially
// else         (2048 blocks): bias rows — 8 rows/block, 1 row/wave, nt loads
// 1 qkv/CU + streaming bias in the second residency slot keeps HBM saturated
// for the whole kernel while MFMA/L2 work hides under it.
__global__ __launch_bounds__(512, 2) void k_mix3(const float* __restrict__ prior,
                                                 const float* __restrict__ x,
                                                 const ushort* __restrict__ wq,
                                                 const ushort* __restrict__ wk,
                                                 const ushort* __restrict__ wv,
                                                 const float* __restrict__ bv,
                                                 float* __restrict__ bias_g,
                                                 ushort* __restrict__ qpre,
                                                 ushort* __restrict__ kb,
                                                 ushort* __restrict__ vb) {
    __shared__ ushort As[32 * 256];       // 16 KB bf16 x-tile, XOR-swizzled
    __shared__ ushort Ws[3 * 256 * 32];   // 48 KB: [mat][e][4 x 16B slots], slot-swizzled
    const int t = threadIdx.x;
    const int w = t >> 6, lane = t & 63;
    const int bid = blockIdx.x;

    if (bid % 9 != 0) {
        // ---- bias block: wave w sums row bidx*8+w (16 KB) with nt loads ----
        const int bidx = bid - bid / 9 - 1;           // 0..2047
        const int row = bidx * 8 + w;
        const f32x4* p = (const f32x4*)(prior + (size_t)row * N_);
        float s0 = 0.f, s1 = 0.f, s2 = 0.f, s3 = 0.f;
#pragma unroll
        for (int i = 0; i < 4; ++i) {
            const f32x4 a = __builtin_nontemporal_load(p + (i * 4 + 0) * 64 + lane);
            const f32x4 b = __builtin_nontemporal_load(p + (i * 4 + 1) * 64 + lane);
            const f32x4 c = __builtin_nontemporal_load(p + (i * 4 + 2) * 64 + lane);
            const f32x4 d = __builtin_nontemporal_load(p + (i * 4 + 3) * 64 + lane);
            s0 += a[0] + a[1] + a[2] + a[3];
            s1 += b[0] + b[1] + b[2] + b[3];
            s2 += c[0] + c[1] + c[2] + c[3];
            s3 += d[0] + d[1] + d[2] + d[3];
        }
        float s = (s0 + s1) + (s2 + s3);
#pragma unroll
        for (int off = 32; off; off >>= 1) s += __shfl_xor(s, off, 64);
        if (lane == 0) bias_g[row] = s * (1.0f / N_);
        return;
    }

    // ---- qkv: two 32-row tiles (round-10 proven body per tile) ----
    const int qidx = bid / 9;             // 0..255
    const int wr = w >> 2, wc = w & 3;    // 2 x 4 waves; wave tile 16 rows x 64 cols
    const int q_ = lane >> 4;             // k-quarter 0..3

#pragma unroll 1
    for (int rt = 0; rt < 2; ++rt) {
        const int rowBase = qidx * 64 + rt * 32;
        __syncthreads();   // protect As/Ws across row-tiles

        {
            const int r = t >> 4;             // 0..31
            const int c0 = (t & 15) * 4;      // 0..60
#pragma unroll
            for (int j = 0; j < 4; ++j) {
                const int c = c0 + j * 64;
                const float4 xv = *(const float4*)(x + (size_t)(rowBase + r) * 256 + c);
                ushort4 o;
                o.x = f2bf(xv.x); o.y = f2bf(xv.y); o.z = f2bf(xv.z); o.w = f2bf(xv.w);
                const int byte = (r * 512 + c * 2) ^ ((r & 7) << 4);
                *(ushort4*)((char*)As + byte) = o;
            }
        }

        f32x4 accq[4] = {}, acck[4] = {}, accv[4] = {};
        for (int kt = 0; kt < 256; kt += 32) {
            __syncthreads();   // covers A-stage on first iteration
#pragma unroll
            for (int j = 0; j < 6; ++j) {
                const int c = j * 512 + t;            // 0..3071
                const int idx = c & 1023;
                const int e = idx >> 2;
                const int pslot = idx & 3;
                const int qsrc = pslot ^ ((e >> 1) & 3);
                const ushort* srcm = (j < 2) ? wq : (j < 4) ? wk : wv;
                GLOAD_LDS16(srcm + (size_t)e * 256 + kt + qsrc * 8, (char*)Ws + c * 16);
            }
            __syncthreads();
            const int r = wr * 16 + (lane & 15);
            const int abyte = (r * 512 + (kt + q_ * 8) * 2) ^ ((r & 7) << 4);
            const bf16x8 af = *(const bf16x8*)((const char*)As + abyte);
#pragma unroll
            for (int n = 0; n < 4; ++n) {
                const int e = wc * 64 + n * 16 + (lane & 15);
                const int wbyte = e * 64 + ((q_ ^ ((e >> 1) & 3)) * 16);
                const bf16x8 bq = *(const bf16x8*)((const char*)Ws + wbyte);
                const bf16x8 bk = *(const bf16x8*)((const char*)Ws + 16384 + wbyte);
                const bf16x8 bw = *(const bf16x8*)((const char*)Ws + 32768 + wbyte);
                accq[n] = MFMA16(af, bq, accq[n]);
                acck[n] = MFMA16(af, bk, acck[n]);
                accv[n] = MFMA16(af, bw, accv[n]);
            }
        }

#pragma unroll
        for (int n = 0; n < 4; ++n)
#pragma unroll
            for (int j = 0; j < 4; ++j) {
                const int rl = wr * 16 + (lane >> 4) * 4 + j;
                const int col = wc * 64 + n * 16 + (lane & 15);
                const size_t go = (size_t)(rowBase + rl) * 256 + col;
                qpre[go] = f2bf(accq[n][j]);
                kb[go]   = f2bf(elu1(acck[n][j]));
                vb[go]   = f2bf(elu1(accv[n][j] + bv[col]));
            }
    }
}

// ---------------- kv[b,h,m,d] = sum_n v*k ; ksum[b,h,d] = sum_n k (bf16 in) --------
// v2: 64 chunks (2048 blocks) — fixes 11.8% occupancy / 1 TB/s starvation.
__global__ __launch_bounds__(256) void k_kvsum(const ushort* __restrict__ kmat,
                                               const ushort* __restrict__ vmat,
                                               float* __restrict__ kv,
                                               float* __restrict__ ksum) {
    const int bh = blockIdx.x;
    const int b = bh >> 3, h = bh & 7;
    const int CH = gridDim.y;
    const int rows = N_ / CH;
    const int tok0 = b * N_ + blockIdx.y * rows;
    __shared__ float kt_[64][32];
    __shared__ float vt_[64][32];
    const int t = threadIdx.x;
    const int m = t >> 3;
    const int lvec = (t & 7) * 4;
    float4 acc = {0.f, 0.f, 0.f, 0.f};
    float4 sk = {0.f, 0.f, 0.f, 0.f};
    for (int r0 = 0; r0 < rows; r0 += 64) {
        __syncthreads();
#pragma unroll
        for (int half = 0; half < 2; ++half) {
            const int rr = (t >> 3) + half * 32;
            const size_t g = (size_t)(tok0 + r0 + rr) * D_ + h * HD_ + lvec;
            const ushort4 ku = *(const ushort4*)(kmat + g);
            const ushort4 vu = *(const ushort4*)(vmat + g);
            kt_[rr][lvec + 0] = __bfloat162float(*(const __hip_bfloat16*)&ku.x);
            kt_[rr][lvec + 1] = __bfloat162float(*(const __hip_bfloat16*)&ku.y);
            kt_[rr][lvec + 2] = __bfloat162float(*(const __hip_bfloat16*)&ku.z);
            kt_[rr][lvec + 3] = __bfloat162float(*(const __hip_bfloat16*)&ku.w);
            vt_[rr][lvec + 0] = __bfloat162float(*(const __hip_bfloat16*)&vu.x);
            vt_[rr][lvec + 1] = __bfloat162float(*(const __hip_bfloat16*)&vu.y);
            vt_[rr][lvec + 2] = __bfloat162float(*(const __hip_bfloat16*)&vu.z);
            vt_[rr][lvec + 3] = __bfloat162float(*(const __hip_bfloat16*)&vu.w);
        }
        __syncthreads();
#pragma unroll 4
        for (int r = 0; r < 64; ++r) {
            const float vv = vt_[r][m];
            const float4 kk = *(const float4*)&kt_[r][lvec];
            acc.x = fmaf(vv, kk.x, acc.x);
            acc.y = fmaf(vv, kk.y, acc.y);
            acc.z = fmaf(vv, kk.z, acc.z);
            acc.w = fmaf(vv, kk.w, acc.w);
            sk.x += kk.x; sk.y += kk.y; sk.z += kk.z; sk.w += kk.w;
        }
    }
    float* kvp = kv + ((size_t)bh * HD_ + m) * HD_ + lvec;
    atomicAdd(kvp + 0, acc.x);
    atomicAdd(kvp + 1, acc.y);
    atomicAdd(kvp + 2, acc.z);
    atomicAdd(kvp + 3, acc.w);
    if (m == 0) {
        float* kp = ksum + (size_t)bh * HD_ + lvec;
        atomicAdd(kp + 0, sk.x);
        atomicAdd(kp + 1, sk.y);
        atomicAdd(kp + 2, sk.z);
        atomicAdd(kp + 3, sk.w);
    }
}

// ================= K3: q-finalize + attn + out-GEMM =================
__global__ __launch_bounds__(512, 2) void k_fusedB(const ushort* __restrict__ qpre,
                                                   const float* __restrict__ bias_g,
                                                   const float* __restrict__ kv,
                                                   const float* __restrict__ ksum,
                                                   const ushort* __restrict__ wo,
                                                   const float* __restrict__ bo,
                                                   float* __restrict__ out) {
    __shared__ ushort qs[64 * 256];    // linear bf16 q tile (32 KB)
    __shared__ ushort at_s[64 * 256];  // swizzled bf16 attn tile (32 KB)
    __shared__ ushort Ws2[256 * 32];   // 16 KB wo slice, slot-swizzled
    const int t = threadIdx.x;
    const int w = t >> 6, lane = t & 63;
    const int tokBase = blockIdx.x * 64;
    const int b = tokBase >> 12;

#pragma unroll
    for (int j = 0; j < 4; ++j) {
        const int chunk = j * 512 + t;
        GLOAD_LDS16(qpre + (size_t)tokBase * 256 + (size_t)chunk * 8,
                    (char*)qs + chunk * 16);
    }

    const int c = t & 255;
    const int h = c >> 5, m = c & 31;
    f32x4 kvr[8], ksr[8];
#pragma unroll
    for (int i = 0; i < 8; ++i) {
        kvr[i] = *(const f32x4*)(kv + (((size_t)(b * H_ + h) * HD_ + m) * HD_) + i * 4);
        ksr[i] = *(const f32x4*)(ksum + (size_t)(b * H_ + h) * HD_ + i * 4);
    }
    __syncthreads();

    {
        const int r = t >> 3;
        const float brow = bias_g[tokBase + r];
        const int cb = (t & 7) * 32;
#pragma unroll
        for (int i = 0; i < 4; ++i) {
            bf16x8 qv = *(bf16x8*)(qs + r * 256 + cb + i * 8);
#pragma unroll
            for (int j = 0; j < 8; ++j) qv[j] = (__bf16)elu1((float)qv[j] + brow);
            *(bf16x8*)(qs + r * 256 + cb + i * 8) = qv;
        }
    }
    __syncthreads();

    for (int tok2 = 0; tok2 < 32; ++tok2) {
        const int tok = tok2 * 2 + (t >> 8);
        float num = 0.f, den = 0.f;
#pragma unroll
        for (int i = 0; i < 4; ++i) {
            const bf16x8 qv = *(const bf16x8*)(qs + tok * 256 + h * HD_ + i * 8);
#pragma unroll
            for (int j = 0; j < 8; ++j) {
                const float qf = (float)qv[j];
                num = fmaf(qf, ((const float*)kvr)[i * 8 + j], num);
                den = fmaf(qf, ((const float*)ksr)[i * 8 + j], den);
            }
        }
        const float a = num / (den + EPSF);
        const int byte = (tok * 512 + c * 2) ^ ((tok & 7) << 4);
        *(ushort*)((char*)at_s + byte) = f2bf(a);
    }

    const int wr = w >> 2, wc = w & 3;
    const int q_ = lane >> 4;
    f32x4 acc[2][4] = {};
    for (int kt = 0; kt < 256; kt += 32) {
        __syncthreads();
#pragma unroll
        for (int j = 0; j < 2; ++j) {
            const int ch = j * 512 + t;           // 0..1023
            const int e = ch >> 2;
            const int pslot = ch & 3;
            const int qsrc = pslot ^ ((e >> 1) & 3);
            GLOAD_LDS16(wo + (size_t)e * 256 + kt + qsrc * 8, (char*)Ws2 + ch * 16);
        }
        __syncthreads();
        bf16x8 af[2];
#pragma unroll
        for (int mm = 0; mm < 2; ++mm) {
            const int r = wr * 32 + mm * 16 + (lane & 15);
            const int byte = (r * 512 + (kt + q_ * 8) * 2) ^ ((r & 7) << 4);
            af[mm] = *(const bf16x8*)((const char*)at_s + byte);
        }
#pragma unroll
        for (int n = 0; n < 4; ++n) {
            const int e = wc * 64 + n * 16 + (lane & 15);
            const int wbyte = e * 64 + ((q_ ^ ((e >> 1) & 3)) * 16);
            const bf16x8 bw = *(const bf16x8*)((const char*)Ws2 + wbyte);
#pragma unroll
            for (int mm = 0; mm < 2; ++mm)
                acc[mm][n] = MFMA16(af[mm], bw, acc[mm][n]);
        }
    }
#pragma unroll
    for (int mm = 0; mm < 2; ++mm)
#pragma unroll
        for (int n = 0; n < 4; ++n)
#pragma unroll
            for (int j = 0; j < 4; ++j) {
                const int row = tokBase + wr * 32 + mm * 16 + (lane >> 4) * 4 + j;
                const int col = wc * 64 + n * 16 + (lane & 15);
                out[(size_t)row * 256 + col] = acc[mm][n][j] + bo[col];
            }
}

extern "C" void kernel_launch(void* const* d_in, const int* in_sizes, int n_in,
                              void* d_out, int out_size, void* d_ws, size_t ws_size,
                              hipStream_t stream) {
    const float* x     = (const float*)d_in[0];
    const float* prior = (const float*)d_in[1];
    const float* Wq    = (const float*)d_in[2];
    const float* Wk    = (const float*)d_in[3];
    const float* Wv    = (const float*)d_in[4];
    const float* bv    = (const float*)d_in[5];
    const float* Wo    = (const float*)d_in[6];
    const float* bo    = (const float*)d_in[7];
    float* out = (float*)d_out;

    // workspace layout
    char* w8 = (char*)d_ws;
    ushort* qpre = (ushort*)w8;                         // 8 MB bf16
    ushort* kb   = qpre + (size_t)TOKENS * D_;
    ushort* vb   = kb + (size_t)TOKENS * D_;
    ushort* wqb  = vb + (size_t)TOKENS * D_;            // 4 x 128 KB bf16
    ushort* wkb  = wqb + 65536;
    ushort* wvb  = wkb + 65536;
    ushort* wob  = wvb + 65536;
    float* kvb   = (float*)(wqb + 4 * 65536);           // 128 KB
    float* ksb   = kvb + 32768;                         // 4 KB
    float* bias  = ksb + 1024;                          // 64 KB

    k_cvt_w<<<128, 256, 0, stream>>>(Wq, Wk, Wv, Wo, wqb, (float4*)kvb);

    k_mix3<<<2304, 512, 0, stream>>>(prior, x, wqb, wkb, wvb, bv, bias, qpre, kb, vb);

    k_kvsum<<<dim3(32, 64), 256, 0, stream>>>(kb, vb, kvb, ksb);

    k_fusedB<<<256, 512, 0, stream>>>(qpre, bias, kvb, ksb, wob, bo, out);
}

// Round 13
// 126.759 us; speedup vs baseline: 11.8101x; 1.1590x over previous
//
#include <hip/hip_runtime.h>
#include <hip/hip_bf16.h>
#include <math.h>

#define B_ 4
#define N_ 4096
#define D_ 256
#define H_ 8
#define HD_ 32
#define TOKENS (B_ * N_)   // 16384
#define EPSF 1e-9f

typedef __bf16 bf16x8 __attribute__((ext_vector_type(8)));
typedef float f32x4 __attribute__((ext_vector_type(4)));
typedef ushort ushort8_t __attribute__((ext_vector_type(8)));

__device__ __forceinline__ float elu1(float x) { return x > 0.f ? x + 1.f : __expf(x); }

__device__ __forceinline__ ushort f2bf(float f) {
    __hip_bfloat16 h = __float2bfloat16(f);
    return *reinterpret_cast<ushort*>(&h);
}

#define GLOAD_LDS16(g, l)                                                              \
    __builtin_amdgcn_global_load_lds((__attribute__((address_space(1))) const void*)(g), \
                                     (__attribute__((address_space(3))) void*)(l), 16, 0, 0)

#define MFMA16(a, b, c) __builtin_amdgcn_mfma_f32_16x16x32_bf16((a), (b), (c), 0, 0, 0)

// ---------------- all four W matrices -> bf16, concatenated; also zero kv/ksum ------
__global__ __launch_bounds__(256) void k_cvt_w(const float* __restrict__ Wq,
                                               const float* __restrict__ Wk,
                                               const float* __restrict__ Wv,
                                               const float* __restrict__ Wo,
                                               ushort* __restrict__ dst,
                                               float4* __restrict__ zbuf) {
    const int i = blockIdx.x * 256 + threadIdx.x;  // 32768 threads x 8 els
    if (i < 8448) zbuf[i] = float4{0.f, 0.f, 0.f, 0.f};
    const int sel = i >> 13;
    const float* src = sel == 0 ? Wq : sel == 1 ? Wk : sel == 2 ? Wv : Wo;
    const int j = i & 8191;
    const float4* s = (const float4*)src + (size_t)j * 2;
    const float4 a = s[0], b = s[1];
    ushort8_t o;
    o[0] = f2bf(a.x); o[1] = f2bf(a.y); o[2] = f2bf(a.z); o[3] = f2bf(a.w);
    o[4] = f2bf(b.x); o[5] = f2bf(b.y); o[6] = f2bf(b.z); o[7] = f2bf(b.w);
    *((ushort8_t*)dst + i) = o;
}

// ================= K1: heterogeneous blocks, qkv FIRST in dispatch order ============
// bid < 256:   qkv GEMM, ONE 64-row tile (80 KB LDS, 2 blocks/CU) — lands 1/CU at t=0
// bid >= 256:  bias rows — 8 rows/block, 1 row/wave, nt loads — streams in 2nd slot
__global__ __launch_bounds__(512, 2) void k_mix4(const float* __restrict__ prior,
                                                 const float* __restrict__ x,
                                                 const ushort* __restrict__ wq,
                                                 const ushort* __restrict__ wk,
                                                 const ushort* __restrict__ wv,
                                                 const float* __restrict__ bv,
                                                 float* __restrict__ bias_g,
                                                 ushort* __restrict__ qpre,
                                                 ushort* __restrict__ kb,
                                                 ushort* __restrict__ vb) {
    __shared__ ushort As[64 * 256];       // 32 KB bf16 x-tile, XOR-swizzled
    __shared__ ushort Ws[3 * 256 * 32];   // 48 KB: [mat][e][4 x 16B slots], slot-swizzled
    const int t = threadIdx.x;
    const int w = t >> 6, lane = t & 63;
    const int bid = blockIdx.x;

    if (bid >= 256) {
        // ---- bias block: wave w sums row (bid-256)*8+w (16 KB) with nt loads ----
        const int row = (bid - 256) * 8 + w;
        const f32x4* p = (const f32x4*)(prior + (size_t)row * N_);
        float s0 = 0.f, s1 = 0.f, s2 = 0.f, s3 = 0.f;
#pragma unroll
        for (int i = 0; i < 4; ++i) {
            const f32x4 a = __builtin_nontemporal_load(p + (i * 4 + 0) * 64 + lane);
            const f32x4 b = __builtin_nontemporal_load(p + (i * 4 + 1) * 64 + lane);
            const f32x4 c = __builtin_nontemporal_load(p + (i * 4 + 2) * 64 + lane);
            const f32x4 d = __builtin_nontemporal_load(p + (i * 4 + 3) * 64 + lane);
            s0 += a[0] + a[1] + a[2] + a[3];
            s1 += b[0] + b[1] + b[2] + b[3];
            s2 += c[0] + c[1] + c[2] + c[3];
            s3 += d[0] + d[1] + d[2] + d[3];
        }
        float s = (s0 + s1) + (s2 + s3);
#pragma unroll
        for (int off = 32; off; off >>= 1) s += __shfl_xor(s, off, 64);
        if (lane == 0) bias_g[row] = s * (1.0f / N_);
        return;
    }

    // ---- qkv: one 64-row tile ----
    const int rowBase = bid * 64;

    // stage x (fp32 -> bf16, swizzled): 32 els/thread
    {
        const int r = t >> 3;             // 0..63
        const int c0 = (t & 7) * 4;       // 0..28
#pragma unroll
        for (int j = 0; j < 8; ++j) {
            const int c = c0 + j * 32;
            const float4 xv = *(const float4*)(x + (size_t)(rowBase + r) * 256 + c);
            ushort4 o;
            o.x = f2bf(xv.x); o.y = f2bf(xv.y); o.z = f2bf(xv.z); o.w = f2bf(xv.w);
            const int byte = (r * 512 + c * 2) ^ ((r & 7) << 4);
            *(ushort4*)((char*)As + byte) = o;
        }
    }

    const int wr = w >> 2, wc = w & 3;    // 2 x 4 waves; wave tile 32 rows x 64 cols
    const int q_ = lane >> 4;             // k-quarter 0..3
    f32x4 accq[2][4] = {}, acck[2][4] = {}, accv[2][4] = {};

    for (int kt = 0; kt < 256; kt += 32) {
        __syncthreads();   // covers A-stage on first iteration
#pragma unroll
        for (int j = 0; j < 6; ++j) {
            const int c = j * 512 + t;            // 0..3071
            const int idx = c & 1023;
            const int e = idx >> 2;
            const int pslot = idx & 3;
            const int qsrc = pslot ^ ((e >> 1) & 3);
            const ushort* srcm = (j < 2) ? wq : (j < 4) ? wk : wv;
            GLOAD_LDS16(srcm + (size_t)e * 256 + kt + qsrc * 8, (char*)Ws + c * 16);
        }
        __syncthreads();
        bf16x8 af[2];
#pragma unroll
        for (int mm = 0; mm < 2; ++mm) {
            const int r = wr * 32 + mm * 16 + (lane & 15);
            const int abyte = (r * 512 + (kt + q_ * 8) * 2) ^ ((r & 7) << 4);
            af[mm] = *(const bf16x8*)((const char*)As + abyte);
        }
#pragma unroll
        for (int n = 0; n < 4; ++n) {
            const int e = wc * 64 + n * 16 + (lane & 15);
            const int wbyte = e * 64 + ((q_ ^ ((e >> 1) & 3)) * 16);
            const bf16x8 bq = *(const bf16x8*)((const char*)Ws + wbyte);
            const bf16x8 bk = *(const bf16x8*)((const char*)Ws + 16384 + wbyte);
            const bf16x8 bw = *(const bf16x8*)((const char*)Ws + 32768 + wbyte);
#pragma unroll
            for (int mm = 0; mm < 2; ++mm) {
                accq[mm][n] = MFMA16(af[mm], bq, accq[mm][n]);
                acck[mm][n] = MFMA16(af[mm], bk, acck[mm][n]);
                accv[mm][n] = MFMA16(af[mm], bw, accv[mm][n]);
            }
        }
    }

#pragma unroll
    for (int mm = 0; mm < 2; ++mm)
#pragma unroll
        for (int n = 0; n < 4; ++n)
#pragma unroll
            for (int j = 0; j < 4; ++j) {
                const int rl = wr * 32 + mm * 16 + (lane >> 4) * 4 + j;
                const int col = wc * 64 + n * 16 + (lane & 15);
                const size_t go = (size_t)(rowBase + rl) * 256 + col;
                qpre[go] = f2bf(accq[mm][n][j]);
                kb[go]   = f2bf(elu1(acck[mm][n][j]));
                vb[go]   = f2bf(elu1(accv[mm][n][j] + bv[col]));
            }
}

// ---------------- kv[b,h,m,d] = sum_n v*k ; ksum[b,h,d] = sum_n k (bf16 in) --------
// dim3(32,32): 1024 blocks (4/CU) — fixes 11.8%-occupancy starvation, bounded atomics.
__global__ __launch_bounds__(256) void k_kvsum(const ushort* __restrict__ kmat,
                                               const ushort* __restrict__ vmat,
                                               float* __restrict__ kv,
                                               float* __restrict__ ksum) {
    const int bh = blockIdx.x;
    const int b = bh >> 3, h = bh & 7;
    const int CH = gridDim.y;
    const int rows = N_ / CH;
    const int tok0 = b * N_ + blockIdx.y * rows;
    __shared__ float kt_[64][32];
    __shared__ float vt_[64][32];
    const int t = threadIdx.x;
    const int m = t >> 3;
    const int lvec = (t & 7) * 4;
    float4 acc = {0.f, 0.f, 0.f, 0.f};
    float4 sk = {0.f, 0.f, 0.f, 0.f};
    for (int r0 = 0; r0 < rows; r0 += 64) {
        __syncthreads();
#pragma unroll
        for (int half = 0; half < 2; ++half) {
            const int rr = (t >> 3) + half * 32;
            const size_t g = (size_t)(tok0 + r0 + rr) * D_ + h * HD_ + lvec;
            const ushort4 ku = *(const ushort4*)(kmat + g);
            const ushort4 vu = *(const ushort4*)(vmat + g);
            kt_[rr][lvec + 0] = __bfloat162float(*(const __hip_bfloat16*)&ku.x);
            kt_[rr][lvec + 1] = __bfloat162float(*(const __hip_bfloat16*)&ku.y);
            kt_[rr][lvec + 2] = __bfloat162float(*(const __hip_bfloat16*)&ku.z);
            kt_[rr][lvec + 3] = __bfloat162float(*(const __hip_bfloat16*)&ku.w);
            vt_[rr][lvec + 0] = __bfloat162float(*(const __hip_bfloat16*)&vu.x);
            vt_[rr][lvec + 1] = __bfloat162float(*(const __hip_bfloat16*)&vu.y);
            vt_[rr][lvec + 2] = __bfloat162float(*(const __hip_bfloat16*)&vu.z);
            vt_[rr][lvec + 3] = __bfloat162float(*(const __hip_bfloat16*)&vu.w);
        }
        __syncthreads();
#pragma unroll 4
        for (int r = 0; r < 64; ++r) {
            const float vv = vt_[r][m];
            const float4 kk = *(const float4*)&kt_[r][lvec];
            acc.x = fmaf(vv, kk.x, acc.x);
            acc.y = fmaf(vv, kk.y, acc.y);
            acc.z = fmaf(vv, kk.z, acc.z);
            acc.w = fmaf(vv, kk.w, acc.w);
            sk.x += kk.x; sk.y += kk.y; sk.z += kk.z; sk.w += kk.w;
        }
    }
    float* kvp = kv + ((size_t)bh * HD_ + m) * HD_ + lvec;
    atomicAdd(kvp + 0, acc.x);
    atomicAdd(kvp + 1, acc.y);
    atomicAdd(kvp + 2, acc.z);
    atomicAdd(kvp + 3, acc.w);
    if (m == 0) {
        float* kp = ksum + (size_t)bh * HD_ + lvec;
        atomicAdd(kp + 0, sk.x);
        atomicAdd(kp + 1, sk.y);
        atomicAdd(kp + 2, sk.z);
        atomicAdd(kp + 3, sk.w);
    }
}

// ================= K3: q-finalize + attn + out-GEMM =================
__global__ __launch_bounds__(512, 2) void k_fusedB(const ushort* __restrict__ qpre,
                                                   const float* __restrict__ bias_g,
                                                   const float* __restrict__ kv,
                                                   const float* __restrict__ ksum,
                                                   const ushort* __restrict__ wo,
                                                   const float* __restrict__ bo,
                                                   float* __restrict__ out) {
    __shared__ ushort qs[64 * 256];    // linear bf16 q tile (32 KB)
    __shared__ ushort at_s[64 * 256];  // swizzled bf16 attn tile (32 KB)
    __shared__ ushort Ws2[256 * 32];   // 16 KB wo slice, slot-swizzled
    const int t = threadIdx.x;
    const int w = t >> 6, lane = t & 63;
    const int tokBase = blockIdx.x * 64;
    const int b = tokBase >> 12;

#pragma unroll
    for (int j = 0; j < 4; ++j) {
        const int chunk = j * 512 + t;
        GLOAD_LDS16(qpre + (size_t)tokBase * 256 + (size_t)chunk * 8,
                    (char*)qs + chunk * 16);
    }

    const int c = t & 255;
    const int h = c >> 5, m = c & 31;
    f32x4 kvr[8], ksr[8];
#pragma unroll
    for (int i = 0; i < 8; ++i) {
        kvr[i] = *(const f32x4*)(kv + (((size_t)(b * H_ + h) * HD_ + m) * HD_) + i * 4);
        ksr[i] = *(const f32x4*)(ksum + (size_t)(b * H_ + h) * HD_ + i * 4);
    }
    __syncthreads();

    {
        const int r = t >> 3;
        const float brow = bias_g[tokBase + r];
        const int cb = (t & 7) * 32;
#pragma unroll
        for (int i = 0; i < 4; ++i) {
            bf16x8 qv = *(bf16x8*)(qs + r * 256 + cb + i * 8);
#pragma unroll
            for (int j = 0; j < 8; ++j) qv[j] = (__bf16)elu1((float)qv[j] + brow);
            *(bf16x8*)(qs + r * 256 + cb + i * 8) = qv;
        }
    }
    __syncthreads();

    for (int tok2 = 0; tok2 < 32; ++tok2) {
        const int tok = tok2 * 2 + (t >> 8);
        float num = 0.f, den = 0.f;
#pragma unroll
        for (int i = 0; i < 4; ++i) {
            const bf16x8 qv = *(const bf16x8*)(qs + tok * 256 + h * HD_ + i * 8);
#pragma unroll
            for (int j = 0; j < 8; ++j) {
                const float qf = (float)qv[j];
                num = fmaf(qf, ((const float*)kvr)[i * 8 + j], num);
                den = fmaf(qf, ((const float*)ksr)[i * 8 + j], den);
            }
        }
        const float a = num / (den + EPSF);
        const int byte = (tok * 512 + c * 2) ^ ((tok & 7) << 4);
        *(ushort*)((char*)at_s + byte) = f2bf(a);
    }

    const int wr = w >> 2, wc = w & 3;
    const int q_ = lane >> 4;
    f32x4 acc[2][4] = {};
    for (int kt = 0; kt < 256; kt += 32) {
        __syncthreads();
#pragma unroll
        for (int j = 0; j < 2; ++j) {
            const int ch = j * 512 + t;           // 0..1023
            const int e = ch >> 2;
            const int pslot = ch & 3;
            const int qsrc = pslot ^ ((e >> 1) & 3);
            GLOAD_LDS16(wo + (size_t)e * 256 + kt + qsrc * 8, (char*)Ws2 + ch * 16);
        }
        __syncthreads();
        bf16x8 af[2];
#pragma unroll
        for (int mm = 0; mm < 2; ++mm) {
            const int r = wr * 32 + mm * 16 + (lane & 15);
            const int byte = (r * 512 + (kt + q_ * 8) * 2) ^ ((r & 7) << 4);
            af[mm] = *(const bf16x8*)((const char*)at_s + byte);
        }
#pragma unroll
        for (int n = 0; n < 4; ++n) {
            const int e = wc * 64 + n * 16 + (lane & 15);
            const int wbyte = e * 64 + ((q_ ^ ((e >> 1) & 3)) * 16);
            const bf16x8 bw = *(const bf16x8*)((const char*)Ws2 + wbyte);
#pragma unroll
            for (int mm = 0; mm < 2; ++mm)
                acc[mm][n] = MFMA16(af[mm], bw, acc[mm][n]);
        }
    }
#pragma unroll
    for (int mm = 0; mm < 2; ++mm)
#pragma unroll
        for (int n = 0; n < 4; ++n)
#pragma unroll
            for (int j = 0; j < 4; ++j) {
                const int row = tokBase + wr * 32 + mm * 16 + (lane >> 4) * 4 + j;
                const int col = wc * 64 + n * 16 + (lane & 15);
                out[(size_t)row * 256 + col] = acc[mm][n][j] + bo[col];
            }
}

extern "C" void kernel_launch(void* const* d_in, const int* in_sizes, int n_in,
                              void* d_out, int out_size, void* d_ws, size_t ws_size,
                              hipStream_t stream) {
    const float* x     = (const float*)d_in[0];
    const float* prior = (const float*)d_in[1];
    const float* Wq    = (const float*)d_in[2];
    const float* Wk    = (const float*)d_in[3];
    const float* Wv    = (const float*)d_in[4];
    const float* bv    = (const float*)d_in[5];
    const float* Wo    = (const float*)d_in[6];
    const float* bo    = (const float*)d_in[7];
    float* out = (float*)d_out;

    // workspace layout
    char* w8 = (char*)d_ws;
    ushort* qpre = (ushort*)w8;                         // 8 MB bf16
    ushort* kb   = qpre + (size_t)TOKENS * D_;
    ushort* vb   = kb + (size_t)TOKENS * D_;
    ushort* wqb  = vb + (size_t)TOKENS * D_;            // 4 x 128 KB bf16
    ushort* wkb  = wqb + 65536;
    ushort* wvb  = wkb + 65536;
    ushort* wob  = wvb + 65536;
    float* kvb   = (float*)(wqb + 4 * 65536);           // 128 KB
    float* ksb   = kvb + 32768;                         // 4 KB
    float* bias  = ksb + 1024;                          // 64 KB

    k_cvt_w<<<128, 256, 0, stream>>>(Wq, Wk, Wv, Wo, wqb, (float4*)kvb);

    k_mix4<<<2304, 512, 0, stream>>>(prior, x, wqb, wkb, wvb, bv, bias, qpre, kb, vb);

    k_kvsum<<<dim3(32, 32), 256, 0, stream>>>(kb, vb, kvb, ksb);

    k_fusedB<<<256, 512, 0, stream>>>(qpre, bias, kvb, ksb, wob, bo, out);
}

// Round 14
// 115.341 us; speedup vs baseline: 12.9793x; 1.0990x over previous
//
#include <hip/hip_runtime.h>
#include <hip/hip_bf16.h>
#include <math.h>

#define B_ 4
#define N_ 4096
#define D_ 256
#define H_ 8
#define HD_ 32
#define TOKENS (B_ * N_)   // 16384
#define EPSF 1e-9f

typedef __bf16 bf16x8 __attribute__((ext_vector_type(8)));
typedef float f32x4 __attribute__((ext_vector_type(4)));
typedef ushort ushort8_t __attribute__((ext_vector_type(8)));

__device__ __forceinline__ float elu1(float x) { return x > 0.f ? x + 1.f : __expf(x); }

__device__ __forceinline__ ushort f2bf(float f) {
    __hip_bfloat16 h = __float2bfloat16(f);
    return *reinterpret_cast<ushort*>(&h);
}

#define GLOAD_LDS16(g, l)                                                              \
    __builtin_amdgcn_global_load_lds((__attribute__((address_space(1))) const void*)(g), \
                                     (__attribute__((address_space(3))) void*)(l), 16, 0, 0)

#define MFMA16(a, b, c) __builtin_amdgcn_mfma_f32_16x16x32_bf16((a), (b), (c), 0, 0, 0)

// ---------------- all four W matrices -> bf16, concatenated; also zero kv/ksum ------
__global__ __launch_bounds__(256) void k_cvt_w(const float* __restrict__ Wq,
                                               const float* __restrict__ Wk,
                                               const float* __restrict__ Wv,
                                               const float* __restrict__ Wo,
                                               ushort* __restrict__ dst,
                                               float4* __restrict__ zbuf) {
    const int i = blockIdx.x * 256 + threadIdx.x;  // 32768 threads x 8 els
    if (i < 8448) zbuf[i] = float4{0.f, 0.f, 0.f, 0.f};
    const int sel = i >> 13;
    const float* src = sel == 0 ? Wq : sel == 1 ? Wk : sel == 2 ? Wv : Wo;
    const int j = i & 8191;
    const float4* s = (const float4*)src + (size_t)j * 2;
    const float4 a = s[0], b = s[1];
    ushort8_t o;
    o[0] = f2bf(a.x); o[1] = f2bf(a.y); o[2] = f2bf(a.z); o[3] = f2bf(a.w);
    o[4] = f2bf(b.x); o[5] = f2bf(b.y); o[6] = f2bf(b.z); o[7] = f2bf(b.w);
    *((ushort8_t*)dst + i) = o;
}

// ================= K1: heterogeneous interleaved blocks (round-10 proven) =============
// bid % 5 == 0 (512 blocks): qkv GEMM tile (32 rows), LDS-staged W, 64 KB LDS (2/CU)
// else        (2048 blocks): bias rows — 8 rows/block, 1 row/wave, nt loads
__global__ __launch_bounds__(512, 2) void k_mix2(const float* __restrict__ prior,
                                                 const float* __restrict__ x,
                                                 const ushort* __restrict__ wq,
                                                 const ushort* __restrict__ wk,
                                                 const ushort* __restrict__ wv,
                                                 const float* __restrict__ bv,
                                                 float* __restrict__ bias_g,
                                                 ushort* __restrict__ qpre,
                                                 ushort* __restrict__ kb,
                                                 ushort* __restrict__ vb) {
    __shared__ ushort As[32 * 256];       // 16 KB bf16 x-tile, XOR-swizzled
    __shared__ ushort Ws[3 * 256 * 32];   // 48 KB: [mat][e][4 x 16B slots], slot-swizzled
    const int t = threadIdx.x;
    const int w = t >> 6, lane = t & 63;
    const int bid = blockIdx.x;

    if (bid % 5 != 0) {
        // ---- bias block: wave w sums row bidx*8+w (16 KB) with nt loads ----
        const int bidx = bid - bid / 5 - 1;           // 0..2047
        const int row = bidx * 8 + w;
        const f32x4* p = (const f32x4*)(prior + (size_t)row * N_);
        float s0 = 0.f, s1 = 0.f, s2 = 0.f, s3 = 0.f;
#pragma unroll
        for (int i = 0; i < 4; ++i) {
            const f32x4 a = __builtin_nontemporal_load(p + (i * 4 + 0) * 64 + lane);
            const f32x4 b = __builtin_nontemporal_load(p + (i * 4 + 1) * 64 + lane);
            const f32x4 c = __builtin_nontemporal_load(p + (i * 4 + 2) * 64 + lane);
            const f32x4 d = __builtin_nontemporal_load(p + (i * 4 + 3) * 64 + lane);
            s0 += a[0] + a[1] + a[2] + a[3];
            s1 += b[0] + b[1] + b[2] + b[3];
            s2 += c[0] + c[1] + c[2] + c[3];
            s3 += d[0] + d[1] + d[2] + d[3];
        }
        float s = (s0 + s1) + (s2 + s3);
#pragma unroll
        for (int off = 32; off; off >>= 1) s += __shfl_xor(s, off, 64);
        if (lane == 0) bias_g[row] = s * (1.0f / N_);
        return;
    }

    // ---- qkv GEMM tile ----
    const int rowBase = (bid / 5) * 32;

    {
        const int r = t >> 4;             // 0..31
        const int c0 = (t & 15) * 4;      // 0..60
#pragma unroll
        for (int j = 0; j < 4; ++j) {
            const int c = c0 + j * 64;
            const float4 xv = *(const float4*)(x + (size_t)(rowBase + r) * 256 + c);
            ushort4 o;
            o.x = f2bf(xv.x); o.y = f2bf(xv.y); o.z = f2bf(xv.z); o.w = f2bf(xv.w);
            const int byte = (r * 512 + c * 2) ^ ((r & 7) << 4);
            *(ushort4*)((char*)As + byte) = o;
        }
    }

    const int wr = w >> 2, wc = w & 3;    // 2 x 4 waves; wave tile 16 rows x 64 cols
    const int q_ = lane >> 4;             // k-quarter 0..3
    f32x4 accq[4] = {}, acck[4] = {}, accv[4] = {};

    for (int kt = 0; kt < 256; kt += 32) {
        __syncthreads();   // also covers the A-stage on first iteration
#pragma unroll
        for (int j = 0; j < 6; ++j) {
            const int c = j * 512 + t;            // 0..3071
            const int idx = c & 1023;
            const int e = idx >> 2;
            const int pslot = idx & 3;
            const int qsrc = pslot ^ ((e >> 1) & 3);
            const ushort* srcm = (j < 2) ? wq : (j < 4) ? wk : wv;
            GLOAD_LDS16(srcm + (size_t)e * 256 + kt + qsrc * 8, (char*)Ws + c * 16);
        }
        __syncthreads();
        const int r = wr * 16 + (lane & 15);
        const int abyte = (r * 512 + (kt + q_ * 8) * 2) ^ ((r & 7) << 4);
        const bf16x8 af = *(const bf16x8*)((const char*)As + abyte);
#pragma unroll
        for (int n = 0; n < 4; ++n) {
            const int e = wc * 64 + n * 16 + (lane & 15);
            const int wbyte = e * 64 + ((q_ ^ ((e >> 1) & 3)) * 16);
            const bf16x8 bq = *(const bf16x8*)((const char*)Ws + wbyte);
            const bf16x8 bk = *(const bf16x8*)((const char*)Ws + 16384 + wbyte);
            const bf16x8 bw = *(const bf16x8*)((const char*)Ws + 32768 + wbyte);
            accq[n] = MFMA16(af, bq, accq[n]);
            acck[n] = MFMA16(af, bk, acck[n]);
            accv[n] = MFMA16(af, bw, accv[n]);
        }
    }

#pragma unroll
    for (int n = 0; n < 4; ++n)
#pragma unroll
        for (int j = 0; j < 4; ++j) {
            const int rl = wr * 16 + (lane >> 4) * 4 + j;
            const int col = wc * 64 + n * 16 + (lane & 15);
            const size_t go = (size_t)(rowBase + rl) * 256 + col;
            qpre[go] = f2bf(accq[n][j]);
            kb[go]   = f2bf(elu1(acck[n][j]));
            vb[go]   = f2bf(elu1(accv[n][j] + bv[col]));
        }
}

// ---------------- kv[b,h,m,d] = sum_n v*k ; ksum[b,h,d] = sum_n k (bf16 in) --------
// dim3(32,32): 1024 blocks (4/CU) — fixes round-11-measured 11.8% occupancy starvation.
__global__ __launch_bounds__(256) void k_kvsum(const ushort* __restrict__ kmat,
                                               const ushort* __restrict__ vmat,
                                               float* __restrict__ kv,
                                               float* __restrict__ ksum) {
    const int bh = blockIdx.x;
    const int b = bh >> 3, h = bh & 7;
    const int CH = gridDim.y;
    const int rows = N_ / CH;
    const int tok0 = b * N_ + blockIdx.y * rows;
    __shared__ float kt_[64][32];
    __shared__ float vt_[64][32];
    const int t = threadIdx.x;
    const int m = t >> 3;
    const int lvec = (t & 7) * 4;
    float4 acc = {0.f, 0.f, 0.f, 0.f};
    float4 sk = {0.f, 0.f, 0.f, 0.f};
    for (int r0 = 0; r0 < rows; r0 += 64) {
        __syncthreads();
#pragma unroll
        for (int half = 0; half < 2; ++half) {
            const int rr = (t >> 3) + half * 32;
            const size_t g = (size_t)(tok0 + r0 + rr) * D_ + h * HD_ + lvec;
            const ushort4 ku = *(const ushort4*)(kmat + g);
            const ushort4 vu = *(const ushort4*)(vmat + g);
            kt_[rr][lvec + 0] = __bfloat162float(*(const __hip_bfloat16*)&ku.x);
            kt_[rr][lvec + 1] = __bfloat162float(*(const __hip_bfloat16*)&ku.y);
            kt_[rr][lvec + 2] = __bfloat162float(*(const __hip_bfloat16*)&ku.z);
            kt_[rr][lvec + 3] = __bfloat162float(*(const __hip_bfloat16*)&ku.w);
            vt_[rr][lvec + 0] = __bfloat162float(*(const __hip_bfloat16*)&vu.x);
            vt_[rr][lvec + 1] = __bfloat162float(*(const __hip_bfloat16*)&vu.y);
            vt_[rr][lvec + 2] = __bfloat162float(*(const __hip_bfloat16*)&vu.z);
            vt_[rr][lvec + 3] = __bfloat162float(*(const __hip_bfloat16*)&vu.w);
        }
        __syncthreads();
#pragma unroll 4
        for (int r = 0; r < 64; ++r) {
            const float vv = vt_[r][m];
            const float4 kk = *(const float4*)&kt_[r][lvec];
            acc.x = fmaf(vv, kk.x, acc.x);
            acc.y = fmaf(vv, kk.y, acc.y);
            acc.z = fmaf(vv, kk.z, acc.z);
            acc.w = fmaf(vv, kk.w, acc.w);
            sk.x += kk.x; sk.y += kk.y; sk.z += kk.z; sk.w += kk.w;
        }
    }
    float* kvp = kv + ((size_t)bh * HD_ + m) * HD_ + lvec;
    atomicAdd(kvp + 0, acc.x);
    atomicAdd(kvp + 1, acc.y);
    atomicAdd(kvp + 2, acc.z);
    atomicAdd(kvp + 3, acc.w);
    if (m == 0) {
        float* kp = ksum + (size_t)bh * HD_ + lvec;
        atomicAdd(kp + 0, sk.x);
        atomicAdd(kp + 1, sk.y);
        atomicAdd(kp + 2, sk.z);
        atomicAdd(kp + 3, sk.w);
    }
}

// ================= K3: q-finalize + attn + out-GEMM =================
__global__ __launch_bounds__(512, 2) void k_fusedB(const ushort* __restrict__ qpre,
                                                   const float* __restrict__ bias_g,
                                                   const float* __restrict__ kv,
                                                   const float* __restrict__ ksum,
                                                   const ushort* __restrict__ wo,
                                                   const float* __restrict__ bo,
                                                   float* __restrict__ out) {
    __shared__ ushort qs[64 * 256];    // linear bf16 q tile (32 KB)
    __shared__ ushort at_s[64 * 256];  // swizzled bf16 attn tile (32 KB)
    __shared__ ushort Ws2[256 * 32];   // 16 KB wo slice, slot-swizzled
    const int t = threadIdx.x;
    const int w = t >> 6, lane = t & 63;
    const int tokBase = blockIdx.x * 64;
    const int b = tokBase >> 12;

#pragma unroll
    for (int j = 0; j < 4; ++j) {
        const int chunk = j * 512 + t;
        GLOAD_LDS16(qpre + (size_t)tokBase * 256 + (size_t)chunk * 8,
                    (char*)qs + chunk * 16);
    }

    const int c = t & 255;
    const int h = c >> 5, m = c & 31;
    f32x4 kvr[8], ksr[8];
#pragma unroll
    for (int i = 0; i < 8; ++i) {
        kvr[i] = *(const f32x4*)(kv + (((size_t)(b * H_ + h) * HD_ + m) * HD_) + i * 4);
        ksr[i] = *(const f32x4*)(ksum + (size_t)(b * H_ + h) * HD_ + i * 4);
    }
    __syncthreads();

    {
        const int r = t >> 3;
        const float brow = bias_g[tokBase + r];
        const int cb = (t & 7) * 32;
#pragma unroll
        for (int i = 0; i < 4; ++i) {
            bf16x8 qv = *(bf16x8*)(qs + r * 256 + cb + i * 8);
#pragma unroll
            for (int j = 0; j < 8; ++j) qv[j] = (__bf16)elu1((float)qv[j] + brow);
            *(bf16x8*)(qs + r * 256 + cb + i * 8) = qv;
        }
    }
    __syncthreads();

    for (int tok2 = 0; tok2 < 32; ++tok2) {
        const int tok = tok2 * 2 + (t >> 8);
        float num = 0.f, den = 0.f;
#pragma unroll
        for (int i = 0; i < 4; ++i) {
            const bf16x8 qv = *(const bf16x8*)(qs + tok * 256 + h * HD_ + i * 8);
#pragma unroll
            for (int j = 0; j < 8; ++j) {
                const float qf = (float)qv[j];
                num = fmaf(qf, ((const float*)kvr)[i * 8 + j], num);
                den = fmaf(qf, ((const float*)ksr)[i * 8 + j], den);
            }
        }
        const float a = num / (den + EPSF);
        const int byte = (tok * 512 + c * 2) ^ ((tok & 7) << 4);
        *(ushort*)((char*)at_s + byte) = f2bf(a);
    }

    const int wr = w >> 2, wc = w & 3;
    const int q_ = lane >> 4;
    f32x4 acc[2][4] = {};
    for (int kt = 0; kt < 256; kt += 32) {
        __syncthreads();
#pragma unroll
        for (int j = 0; j < 2; ++j) {
            const int ch = j * 512 + t;           // 0..1023
            const int e = ch >> 2;
            const int pslot = ch & 3;
            const int qsrc = pslot ^ ((e >> 1) & 3);
            GLOAD_LDS16(wo + (size_t)e * 256 + kt + qsrc * 8, (char*)Ws2 + ch * 16);
        }
        __syncthreads();
        bf16x8 af[2];
#pragma unroll
        for (int mm = 0; mm < 2; ++mm) {
            const int r = wr * 32 + mm * 16 + (lane & 15);
            const int byte = (r * 512 + (kt + q_ * 8) * 2) ^ ((r & 7) << 4);
            af[mm] = *(const bf16x8*)((const char*)at_s + byte);
        }
#pragma unroll
        for (int n = 0; n < 4; ++n) {
            const int e = wc * 64 + n * 16 + (lane & 15);
            const int wbyte = e * 64 + ((q_ ^ ((e >> 1) & 3)) * 16);
            const bf16x8 bw = *(const bf16x8*)((const char*)Ws2 + wbyte);
#pragma unroll
            for (int mm = 0; mm < 2; ++mm)
                acc[mm][n] = MFMA16(af[mm], bw, acc[mm][n]);
        }
    }
#pragma unroll
    for (int mm = 0; mm < 2; ++mm)
#pragma unroll
        for (int n = 0; n < 4; ++n)
#pragma unroll
            for (int j = 0; j < 4; ++j) {
                const int row = tokBase + wr * 32 + mm * 16 + (lane >> 4) * 4 + j;
                const int col = wc * 64 + n * 16 + (lane & 15);
                out[(size_t)row * 256 + col] = acc[mm][n][j] + bo[col];
            }
}

extern "C" void kernel_launch(void* const* d_in, const int* in_sizes, int n_in,
                              void* d_out, int out_size, void* d_ws, size_t ws_size,
                              hipStream_t stream) {
    const float* x     = (const float*)d_in[0];
    const float* prior = (const float*)d_in[1];
    const float* Wq    = (const float*)d_in[2];
    const float* Wk    = (const float*)d_in[3];
    const float* Wv    = (const float*)d_in[4];
    const float* bv    = (const float*)d_in[5];
    const float* Wo    = (const float*)d_in[6];
    const float* bo    = (const float*)d_in[7];
    float* out = (float*)d_out;

    // workspace layout
    char* w8 = (char*)d_ws;
    ushort* qpre = (ushort*)w8;                         // 8 MB bf16
    ushort* kb   = qpre + (size_t)TOKENS * D_;
    ushort* vb   = kb + (size_t)TOKENS * D_;
    ushort* wqb  = vb + (size_t)TOKENS * D_;            // 4 x 128 KB bf16
    ushort* wkb  = wqb + 65536;
    ushort* wvb  = wkb + 65536;
    ushort* wob  = wvb + 65536;
    float* kvb   = (float*)(wqb + 4 * 65536);           // 128 KB
    float* ksb   = kvb + 32768;                         // 4 KB
    float* bias  = ksb + 1024;                          // 64 KB

    k_cvt_w<<<128, 256, 0, stream>>>(Wq, Wk, Wv, Wo, wqb, (float4*)kvb);

    k_mix2<<<2560, 512, 0, stream>>>(prior, x, wqb, wkb, wvb, bv, bias, qpre, kb, vb);

    k_kvsum<<<dim3(32, 32), 256, 0, stream>>>(kb, vb, kvb, ksb);

    k_fusedB<<<256, 512, 0, stream>>>(qpre, bias, kvb, ksb, wob, bo, out);
}

// Round 15
// 103.300 us; speedup vs baseline: 14.4922x; 1.1166x over previous
//
#include <hip/hip_runtime.h>
#include <hip/hip_bf16.h>
#include <math.h>

#define B_ 4
#define N_ 4096
#define D_ 256
#define H_ 8
#define HD_ 32
#define TOKENS (B_ * N_)   // 16384
#define EPSF 1e-9f
#define KV_CH 64           // kv partial chunks

typedef __bf16 bf16x8 __attribute__((ext_vector_type(8)));
typedef float f32x4 __attribute__((ext_vector_type(4)));
typedef ushort ushort8_t __attribute__((ext_vector_type(8)));

__device__ __forceinline__ float elu1(float x) { return x > 0.f ? x + 1.f : __expf(x); }

__device__ __forceinline__ ushort f2bf(float f) {
    __hip_bfloat16 h = __float2bfloat16(f);
    return *reinterpret_cast<ushort*>(&h);
}

#define GLOAD_LDS16(g, l)                                                              \
    __builtin_amdgcn_global_load_lds((__attribute__((address_space(1))) const void*)(g), \
                                     (__attribute__((address_space(3))) void*)(l), 16, 0, 0)

#define MFMA16(a, b, c) __builtin_amdgcn_mfma_f32_16x16x32_bf16((a), (b), (c), 0, 0, 0)

// ---------------- all four W matrices -> bf16, concatenated ----------------
__global__ __launch_bounds__(256) void k_cvt_w(const float* __restrict__ Wq,
                                               const float* __restrict__ Wk,
                                               const float* __restrict__ Wv,
                                               const float* __restrict__ Wo,
                                               ushort* __restrict__ dst) {
    const int i = blockIdx.x * 256 + threadIdx.x;  // 32768 threads x 8 els
    const int sel = i >> 13;
    const float* src = sel == 0 ? Wq : sel == 1 ? Wk : sel == 2 ? Wv : Wo;
    const int j = i & 8191;
    const float4* s = (const float4*)src + (size_t)j * 2;
    const float4 a = s[0], b = s[1];
    ushort8_t o;
    o[0] = f2bf(a.x); o[1] = f2bf(a.y); o[2] = f2bf(a.z); o[3] = f2bf(a.w);
    o[4] = f2bf(b.x); o[5] = f2bf(b.y); o[6] = f2bf(b.z); o[7] = f2bf(b.w);
    *((ushort8_t*)dst + i) = o;
}

// ================= K1: heterogeneous interleaved blocks (round-10 proven) =============
// bid % 5 == 0 (512 blocks): qkv GEMM tile (32 rows), LDS-staged W, 64 KB LDS (2/CU)
// else        (2048 blocks): bias rows — 8 rows/block, 1 row/wave, nt loads
__global__ __launch_bounds__(512, 2) void k_mix2(const float* __restrict__ prior,
                                                 const float* __restrict__ x,
                                                 const ushort* __restrict__ wq,
                                                 const ushort* __restrict__ wk,
                                                 const ushort* __restrict__ wv,
                                                 const float* __restrict__ bv,
                                                 float* __restrict__ bias_g,
                                                 ushort* __restrict__ qpre,
                                                 ushort* __restrict__ kb,
                                                 ushort* __restrict__ vb) {
    __shared__ ushort As[32 * 256];       // 16 KB bf16 x-tile, XOR-swizzled
    __shared__ ushort Ws[3 * 256 * 32];   // 48 KB: [mat][e][4 x 16B slots], slot-swizzled
    const int t = threadIdx.x;
    const int w = t >> 6, lane = t & 63;
    const int bid = blockIdx.x;

    if (bid % 5 != 0) {
        // ---- bias block: wave w sums row bidx*8+w (16 KB) with nt loads ----
        const int bidx = bid - bid / 5 - 1;           // 0..2047
        const int row = bidx * 8 + w;
        const f32x4* p = (const f32x4*)(prior + (size_t)row * N_);
        float s0 = 0.f, s1 = 0.f, s2 = 0.f, s3 = 0.f;
#pragma unroll
        for (int i = 0; i < 4; ++i) {
            const f32x4 a = __builtin_nontemporal_load(p + (i * 4 + 0) * 64 + lane);
            const f32x4 b = __builtin_nontemporal_load(p + (i * 4 + 1) * 64 + lane);
            const f32x4 c = __builtin_nontemporal_load(p + (i * 4 + 2) * 64 + lane);
            const f32x4 d = __builtin_nontemporal_load(p + (i * 4 + 3) * 64 + lane);
            s0 += a[0] + a[1] + a[2] + a[3];
            s1 += b[0] + b[1] + b[2] + b[3];
            s2 += c[0] + c[1] + c[2] + c[3];
            s3 += d[0] + d[1] + d[2] + d[3];
        }
        float s = (s0 + s1) + (s2 + s3);
#pragma unroll
        for (int off = 32; off; off >>= 1) s += __shfl_xor(s, off, 64);
        if (lane == 0) bias_g[row] = s * (1.0f / N_);
        return;
    }

    // ---- qkv GEMM tile ----
    const int rowBase = (bid / 5) * 32;

    {
        const int r = t >> 4;             // 0..31
        const int c0 = (t & 15) * 4;      // 0..60
#pragma unroll
        for (int j = 0; j < 4; ++j) {
            const int c = c0 + j * 64;
            const float4 xv = *(const float4*)(x + (size_t)(rowBase + r) * 256 + c);
            ushort4 o;
            o.x = f2bf(xv.x); o.y = f2bf(xv.y); o.z = f2bf(xv.z); o.w = f2bf(xv.w);
            const int byte = (r * 512 + c * 2) ^ ((r & 7) << 4);
            *(ushort4*)((char*)As + byte) = o;
        }
    }

    const int wr = w >> 2, wc = w & 3;    // 2 x 4 waves; wave tile 16 rows x 64 cols
    const int q_ = lane >> 4;             // k-quarter 0..3
    f32x4 accq[4] = {}, acck[4] = {}, accv[4] = {};

    for (int kt = 0; kt < 256; kt += 32) {
        __syncthreads();   // also covers the A-stage on first iteration
#pragma unroll
        for (int j = 0; j < 6; ++j) {
            const int c = j * 512 + t;            // 0..3071
            const int idx = c & 1023;
            const int e = idx >> 2;
            const int pslot = idx & 3;
            const int qsrc = pslot ^ ((e >> 1) & 3);
            const ushort* srcm = (j < 2) ? wq : (j < 4) ? wk : wv;
            GLOAD_LDS16(srcm + (size_t)e * 256 + kt + qsrc * 8, (char*)Ws + c * 16);
        }
        __syncthreads();
        const int r = wr * 16 + (lane & 15);
        const int abyte = (r * 512 + (kt + q_ * 8) * 2) ^ ((r & 7) << 4);
        const bf16x8 af = *(const bf16x8*)((const char*)As + abyte);
#pragma unroll
        for (int n = 0; n < 4; ++n) {
            const int e = wc * 64 + n * 16 + (lane & 15);
            const int wbyte = e * 64 + ((q_ ^ ((e >> 1) & 3)) * 16);
            const bf16x8 bq = *(const bf16x8*)((const char*)Ws + wbyte);
            const bf16x8 bk = *(const bf16x8*)((const char*)Ws + 16384 + wbyte);
            const bf16x8 bw = *(const bf16x8*)((const char*)Ws + 32768 + wbyte);
            accq[n] = MFMA16(af, bq, accq[n]);
            acck[n] = MFMA16(af, bk, acck[n]);
            accv[n] = MFMA16(af, bw, accv[n]);
        }
    }

#pragma unroll
    for (int n = 0; n < 4; ++n)
#pragma unroll
        for (int j = 0; j < 4; ++j) {
            const int rl = wr * 16 + (lane >> 4) * 4 + j;
            const int col = wc * 64 + n * 16 + (lane & 15);
            const size_t go = (size_t)(rowBase + rl) * 256 + col;
            qpre[go] = f2bf(accq[n][j]);
            kb[go]   = f2bf(elu1(acck[n][j]));
            vb[go]   = f2bf(elu1(accv[n][j] + bv[col]));
        }
}

// ---------------- Stage A: partial kv/ksum per (bh, chunk) — NO atomics ----------------
// grid (32, 64): block handles one 64-row chunk; stores 1056-float partial to own slot.
__global__ __launch_bounds__(256) void k_kvpart(const ushort* __restrict__ kmat,
                                                const ushort* __restrict__ vmat,
                                                float* __restrict__ part) {
    const int bh = blockIdx.x;
    const int b = bh >> 3, h = bh & 7;
    const int tok0 = b * N_ + blockIdx.y * 64;
    __shared__ float kt_[64][32];
    __shared__ float vt_[64][32];
    const int t = threadIdx.x;
    const int m = t >> 3;
    const int lvec = (t & 7) * 4;
#pragma unroll
    for (int half = 0; half < 2; ++half) {
        const int rr = (t >> 3) + half * 32;
        const size_t g = (size_t)(tok0 + rr) * D_ + h * HD_ + lvec;
        const ushort4 ku = *(const ushort4*)(kmat + g);
        const ushort4 vu = *(const ushort4*)(vmat + g);
        kt_[rr][lvec + 0] = __bfloat162float(*(const __hip_bfloat16*)&ku.x);
        kt_[rr][lvec + 1] = __bfloat162float(*(const __hip_bfloat16*)&ku.y);
        kt_[rr][lvec + 2] = __bfloat162float(*(const __hip_bfloat16*)&ku.z);
        kt_[rr][lvec + 3] = __bfloat162float(*(const __hip_bfloat16*)&ku.w);
        vt_[rr][lvec + 0] = __bfloat162float(*(const __hip_bfloat16*)&vu.x);
        vt_[rr][lvec + 1] = __bfloat162float(*(const __hip_bfloat16*)&vu.y);
        vt_[rr][lvec + 2] = __bfloat162float(*(const __hip_bfloat16*)&vu.z);
        vt_[rr][lvec + 3] = __bfloat162float(*(const __hip_bfloat16*)&vu.w);
    }
    __syncthreads();
    float4 acc = {0.f, 0.f, 0.f, 0.f};
    float4 sk = {0.f, 0.f, 0.f, 0.f};
#pragma unroll 4
    for (int r = 0; r < 64; ++r) {
        const float vv = vt_[r][m];
        const float4 kk = *(const float4*)&kt_[r][lvec];
        acc.x = fmaf(vv, kk.x, acc.x);
        acc.y = fmaf(vv, kk.y, acc.y);
        acc.z = fmaf(vv, kk.z, acc.z);
        acc.w = fmaf(vv, kk.w, acc.w);
        sk.x += kk.x; sk.y += kk.y; sk.z += kk.z; sk.w += kk.w;
    }
    float* outp = part + ((size_t)blockIdx.y * 32 + bh) * 1056;
    *(float4*)(outp + m * 32 + lvec) = acc;
    if (m == 0) *(float4*)(outp + 1024 + lvec) = sk;
}

// ---------------- Stage B: reduce 64 partials -> kv/ksum (overwrite) ----------------
__global__ __launch_bounds__(256) void k_kvred(const float* __restrict__ part,
                                               float* __restrict__ kv,
                                               float* __restrict__ ksum) {
    const int i = blockIdx.x * 256 + threadIdx.x;   // 0..33791
    if (i >= 32 * 1056) return;
    const int bh = i / 1056, r = i - bh * 1056;
    float s = 0.f;
#pragma unroll 8
    for (int c = 0; c < KV_CH; ++c) s += part[((size_t)c * 32 + bh) * 1056 + r];
    if (r < 1024) kv[(size_t)bh * 1024 + r] = s;
    else          ksum[(size_t)bh * 32 + (r - 1024)] = s;
}

// ================= K3: q-finalize + attn + out-GEMM =================
__global__ __launch_bounds__(512, 2) void k_fusedB(const ushort* __restrict__ qpre,
                                                   const float* __restrict__ bias_g,
                                                   const float* __restrict__ kv,
                                                   const float* __restrict__ ksum,
                                                   const ushort* __restrict__ wo,
                                                   const float* __restrict__ bo,
                                                   float* __restrict__ out) {
    __shared__ ushort qs[64 * 256];    // linear bf16 q tile (32 KB)
    __shared__ ushort at_s[64 * 256];  // swizzled bf16 attn tile (32 KB)
    __shared__ ushort Ws2[256 * 32];   // 16 KB wo slice, slot-swizzled
    const int t = threadIdx.x;
    const int w = t >> 6, lane = t & 63;
    const int tokBase = blockIdx.x * 64;
    const int b = tokBase >> 12;

#pragma unroll
    for (int j = 0; j < 4; ++j) {
        const int chunk = j * 512 + t;
        GLOAD_LDS16(qpre + (size_t)tokBase * 256 + (size_t)chunk * 8,
                    (char*)qs + chunk * 16);
    }

    const int c = t & 255;
    const int h = c >> 5, m = c & 31;
    f32x4 kvr[8], ksr[8];
#pragma unroll
    for (int i = 0; i < 8; ++i) {
        kvr[i] = *(const f32x4*)(kv + (((size_t)(b * H_ + h) * HD_ + m) * HD_) + i * 4);
        ksr[i] = *(const f32x4*)(ksum + (size_t)(b * H_ + h) * HD_ + i * 4);
    }
    __syncthreads();

    {
        const int r = t >> 3;
        const float brow = bias_g[tokBase + r];
        const int cb = (t & 7) * 32;
#pragma unroll
        for (int i = 0; i < 4; ++i) {
            bf16x8 qv = *(bf16x8*)(qs + r * 256 + cb + i * 8);
#pragma unroll
            for (int j = 0; j < 8; ++j) qv[j] = (__bf16)elu1((float)qv[j] + brow);
            *(bf16x8*)(qs + r * 256 + cb + i * 8) = qv;
        }
    }
    __syncthreads();

    for (int tok2 = 0; tok2 < 32; ++tok2) {
        const int tok = tok2 * 2 + (t >> 8);
        float num = 0.f, den = 0.f;
#pragma unroll
        for (int i = 0; i < 4; ++i) {
            const bf16x8 qv = *(const bf16x8*)(qs + tok * 256 + h * HD_ + i * 8);
#pragma unroll
            for (int j = 0; j < 8; ++j) {
                const float qf = (float)qv[j];
                num = fmaf(qf, ((const float*)kvr)[i * 8 + j], num);
                den = fmaf(qf, ((const float*)ksr)[i * 8 + j], den);
            }
        }
        const float a = num / (den + EPSF);
        const int byte = (tok * 512 + c * 2) ^ ((tok & 7) << 4);
        *(ushort*)((char*)at_s + byte) = f2bf(a);
    }

    const int wr = w >> 2, wc = w & 3;
    const int q_ = lane >> 4;
    f32x4 acc[2][4] = {};
    for (int kt = 0; kt < 256; kt += 32) {
        __syncthreads();
#pragma unroll
        for (int j = 0; j < 2; ++j) {
            const int ch = j * 512 + t;           // 0..1023
            const int e = ch >> 2;
            const int pslot = ch & 3;
            const int qsrc = pslot ^ ((e >> 1) & 3);
            GLOAD_LDS16(wo + (size_t)e * 256 + kt + qsrc * 8, (char*)Ws2 + ch * 16);
        }
        __syncthreads();
        bf16x8 af[2];
#pragma unroll
        for (int mm = 0; mm < 2; ++mm) {
            const int r = wr * 32 + mm * 16 + (lane & 15);
            const int byte = (r * 512 + (kt + q_ * 8) * 2) ^ ((r & 7) << 4);
            af[mm] = *(const bf16x8*)((const char*)at_s + byte);
        }
#pragma unroll
        for (int n = 0; n < 4; ++n) {
            const int e = wc * 64 + n * 16 + (lane & 15);
            const int wbyte = e * 64 + ((q_ ^ ((e >> 1) & 3)) * 16);
            const bf16x8 bw = *(const bf16x8*)((const char*)Ws2 + wbyte);
#pragma unroll
            for (int mm = 0; mm < 2; ++mm)
                acc[mm][n] = MFMA16(af[mm], bw, acc[mm][n]);
        }
    }
#pragma unroll
    for (int mm = 0; mm < 2; ++mm)
#pragma unroll
        for (int n = 0; n < 4; ++n)
#pragma unroll
            for (int j = 0; j < 4; ++j) {
                const int row = tokBase + wr * 32 + mm * 16 + (lane >> 4) * 4 + j;
                const int col = wc * 64 + n * 16 + (lane & 15);
                out[(size_t)row * 256 + col] = acc[mm][n][j] + bo[col];
            }
}

extern "C" void kernel_launch(void* const* d_in, const int* in_sizes, int n_in,
                              void* d_out, int out_size, void* d_ws, size_t ws_size,
                              hipStream_t stream) {
    const float* x     = (const float*)d_in[0];
    const float* prior = (const float*)d_in[1];
    const float* Wq    = (const float*)d_in[2];
    const float* Wk    = (const float*)d_in[3];
    const float* Wv    = (const float*)d_in[4];
    const float* bv    = (const float*)d_in[5];
    const float* Wo    = (const float*)d_in[6];
    const float* bo    = (const float*)d_in[7];
    float* out = (float*)d_out;

    // workspace layout
    char* w8 = (char*)d_ws;
    ushort* qpre = (ushort*)w8;                         // 8 MB bf16
    ushort* kb   = qpre + (size_t)TOKENS * D_;
    ushort* vb   = kb + (size_t)TOKENS * D_;
    ushort* wqb  = vb + (size_t)TOKENS * D_;            // 4 x 128 KB bf16
    ushort* wkb  = wqb + 65536;
    ushort* wvb  = wkb + 65536;
    ushort* wob  = wvb + 65536;
    float* kvb   = (float*)(wqb + 4 * 65536);           // 128 KB
    float* ksb   = kvb + 32768;                         // 4 KB
    float* bias  = ksb + 1024;                          // 64 KB
    float* part  = bias + TOKENS;                       // 64*32*1056*4 = 8.65 MB

    k_cvt_w<<<128, 256, 0, stream>>>(Wq, Wk, Wv, Wo, wqb);

    k_mix2<<<2560, 512, 0, stream>>>(prior, x, wqb, wkb, wvb, bv, bias, qpre, kb, vb);

    k_kvpart<<<dim3(32, KV_CH), 256, 0, stream>>>(kb, vb, part);
    k_kvred<<<132, 256, 0, stream>>>(part, kvb, ksb);

    k_fusedB<<<256, 512, 0, stream>>>(qpre, bias, kvb, ksb, wob, bo, out);
}